// Round 8
// baseline (399.467 us; speedup 1.0000x reference)
//
#include <hip/hip_runtime.h>
#include <math.h>

#define BATCH 2048
#define N_TIME 2048
#define INPUT_SIZE 28
#define OUTPUT_SIZE 7
#define N_S 4
#define PERIOD 7
#define EMBED 9
#define SEAS_LEN (N_TIME + PERIOD)       // 2055
#define W_COUNT 288                      // len(range(0, 2014, 7))
#define WB_COUNT (W_COUNT * BATCH)       // 589824
#define INS_COLS 67                      // 28 + 35 + 4
#define OUT0_SIZE (WB_COUNT * INS_COLS)  // 39,518,208
#define OUT1_SIZE (WB_COUNT * OUTPUT_SIZE) // 4,128,768
#define LEV_SIZE (BATCH * N_TIME)
#define SEAS_SIZE (BATCH * SEAS_LEN)

// Work split (PROVEN r4/r6 two-kernel shape):
//   kernel1 scan blocks (0..31): producer-consumer ES recurrence.
//   kernel1 copy blocks (32..511): out0 cols [28,67) (X,S) + out1.
//   kernel2: out0 cols [0,28) (y_in; needs levels/seasonal).
// HARD LESSON (r3/r5/r7, three collapses): any flags/steal-loops/ABI calls
// co-compiled into this kernel drops the scan's y-buffer SROA (VGPR 256->132,
// ~33 MB scratch traffic). Scan kernel stays minimal; yin stays separate.
//
// ROUND-8 CHANGE (scan arithmetic untouched): 4 tile-buffers, ONE barrier per
// 2 chunks (was 2-buffer, barrier per chunk). Rationale: the consumer's ~80
// global stores/chunk contend with 480 copy blocks for HBM; a latency spike
// makes drain > compute and the PRODUCER blocks at the rendezvous. A 2-chunk
// window absorbs spikes. 133 KB LDS also forces 1 block/CU -> scan blocks no
// longer share their CU with a copy block.
#define M0_COPY (WB_COUNT * 39)              // 23,003,136 (X+S cols)
#define M_COPY  (M0_COPY + OUT1_SIZE)        // 27,131,904
#define COPY_BLOCKS 480
#define GRID1 (32 + COPY_BLOCKS)
#define N_YIN (WB_COUNT * INPUT_SIZE)        // 16,515,072 = 64512*256
#define CUNROLL 16

// ---------------------------------------------------------------------------
// Scan core (r6-proven recurrence): producer = software-pipelined, modular-
// slot sbuf/rbuf (s_k = ns_{k-7} known 7 steps early -> level update is ONE
// carried fma); consumer = tile transpose + coalesced stores.
// scan_chunk no longer ends with a barrier — the caller places one per PAIR.
// ---------------------------------------------------------------------------
struct ScanState {
    float lev, lsms, seas_sms, oma, oms;
    float sbuf[PERIOD];   // slot j%7 holds s_{t0+j}
    float rbuf[PERIOD];   // slot j%7 holds lsms * rcp(s_{t0+j})
    float yp, sp, rnlp, rnsp;
};

template<bool FIRST, bool LAST, bool PREF>
__device__ __forceinline__ void scan_chunk(
    int base, int l,
    const float* __restrict__ Yb,
    float (&cur)[64], float (&nxt)[64],
    float (*__restrict__ tl)[65], float (*__restrict__ ts)[65],
    ScanState& st)
{
    if (PREF) {
#pragma unroll
        for (int k = 0; k < 64; k += 4)
            *(float4*)&nxt[k] = *(const float4*)(Yb + base + 64 + k);
    }
    tl[l][0] = st.lev;                 // carry-in: levels col `base`
#pragma unroll
    for (int k = 0; k < 64; ++k) {
        if (!LAST || k < 63) {         // last chunk has 63 steps
            float y  = (k < 63) ? cur[k + 1] : nxt[0];
            float s0 = st.sbuf[k % 7];
            float nl = fmaf(st.oma, st.lev, y * st.rbuf[k % 7]);
            st.lev = nl;
            tl[l][k + 1] = nl;         // levels col base+k+1
            if (!FIRST || k > 0) {     // finish PREVIOUS step's seasonal
                float u  = st.yp * st.rnlp;
                float ns = fmaf(st.oms, st.sp, st.seas_sms * u);
                ts[l][k] = ns;                 // seasonal col base+7+k
                st.sbuf[(k + 6) % 7] = ns;     // consumed at k+6
                if (!FIRST || k > 1)
                    st.rbuf[(k + 5) % 7] = st.lsms * st.rnsp; // for k+5
                st.rnsp = __builtin_amdgcn_rcpf(ns);
            }
            float rnl = __builtin_amdgcn_rcpf(nl);   // consumed next step
            st.yp = y; st.sp = s0; st.rnlp = rnl;
        }
    }
    if (LAST) {                        // drain pipeline: ns_{2046}
        float u  = st.yp * st.rnlp;
        float ns = fmaf(st.oms, st.sp, st.seas_sms * u);
        ts[l][63] = ns;                // seasonal col 2054
    } else {
        // slot-base drift: next chunk's t0 advances by 64 (== 1 mod 7)
        float t0s = st.sbuf[0], t0r = st.rbuf[0];
#pragma unroll
        for (int q = 0; q < PERIOD - 1; ++q) {
            st.sbuf[q] = st.sbuf[q + 1];
            st.rbuf[q] = st.rbuf[q + 1];
        }
        st.sbuf[PERIOD - 1] = t0s;
        st.rbuf[PERIOD - 1] = t0r;
    }
}

__device__ __forceinline__ void drain_chunk(
    int base, int jr, int km, int r0,
    const float (*__restrict__ tl)[65], const float (*__restrict__ ts)[65],
    float* __restrict__ levels, float* __restrict__ seasonal)
{
#pragma unroll
    for (int j0 = 0; j0 < 64; j0 += 4) {
        int j = j0 + jr;               // tile row = local batch row
        float vl[4], vs[4];
#pragma unroll
        for (int i = 0; i < 4; ++i) { vl[i] = tl[j][km + i]; vs[i] = ts[j][km + i]; }
        float4 v4; v4.x = vl[0]; v4.y = vl[1]; v4.z = vl[2]; v4.w = vl[3];
        *(float4*)(levels + (size_t)(r0 + j) * N_TIME + base + km) = v4;
        float* srow = seasonal + (size_t)(r0 + j) * SEAS_LEN + base + 7 + km;
#pragma unroll
        for (int i = 0; i < 4; ++i) srow[i] = vs[i];
    }
}

__device__ __forceinline__ void copy_addr(
    unsigned g,
    const float* __restrict__ Y, const float* __restrict__ X,
    const float* __restrict__ S,
    float* __restrict__ out0, float* __restrict__ out1,
    const float*& src, float*& dst)
{
    if (g < M0_COPY) {                 // out0 cols 28..66 (X then S)
        unsigned wb = g / 39u;
        int jj = (int)(g - wb * 39u);
        int w  = (int)(wb >> 11);
        int b  = (int)(wb & (BATCH - 1));
        src = (jj < 35) ? &X[b * N_TIME + w * 7 + jj]
                        : &S[b * N_S + (jj - 35)];
        dst = &out0[(size_t)wb * 67u + 28u + (unsigned)jj];
    } else {                           // out1
        unsigned e  = g - M0_COPY;
        unsigned wb = e / 7u;
        int m  = (int)(e - wb * 7u);
        int w  = (int)(wb >> 11);
        int b  = (int)(wb & (BATCH - 1));
        src = &Y[b * N_TIME + w * 7 + INPUT_SIZE + m];
        dst = &out1[e];
    }
}

__global__ __launch_bounds__(128, 1) void es_scan_plus(
    const float* __restrict__ Y, const int* __restrict__ idxs,
    const float* __restrict__ emb, const float* __restrict__ X,
    const float* __restrict__ S,
    float* __restrict__ levels, float* __restrict__ seasonal,
    float* __restrict__ out0, float* __restrict__ out1)
{
    __shared__ float tl[4][64][65];    // 4 buffers: pair {0,1} / {2,3}
    __shared__ float ts[4][64][65];    // total 133,120 B -> 1 block/CU
    const int tid = threadIdx.x;
    const int l   = tid & 63;

    if (blockIdx.x >= 32) {
        // ------- copy blocks: 16-deep gather/scatter (64 B in flight/thread) ---
        const unsigned stride = COPY_BLOCKS * 128;
        unsigned g = (blockIdx.x - 32) * 128 + tid;
#pragma unroll 1
        for (; g + (CUNROLL - 1) * stride < M_COPY; g += stride * CUNROLL) {
            const float* src[CUNROLL]; float* dst[CUNROLL]; float v[CUNROLL];
#pragma unroll
            for (int u = 0; u < CUNROLL; ++u)
                copy_addr(g + (unsigned)u * stride, Y, X, S, out0, out1, src[u], dst[u]);
#pragma unroll
            for (int u = 0; u < CUNROLL; ++u) v[u] = *src[u];
#pragma unroll
            for (int u = 0; u < CUNROLL; ++u) *dst[u] = v[u];
        }
#pragma unroll 1
        for (; g < M_COPY; g += stride) {
            const float* src; float* dst;
            copy_addr(g, Y, X, S, out0, out1, src, dst);
            *dst = *src;
        }
        return;
    }

    const int r0 = blockIdx.x * 64;
    if (tid < 64) {
        // ---------------- producer wave: the recurrence ----------------
        const int b = r0 + l;
        const float* Yb = Y + (size_t)b * N_TIME;
        const float* e  = emb + (size_t)idxs[b] * EMBED;
        ScanState st;
        st.lsms     = 1.0f / (1.0f + __expf(-e[0]));
        st.seas_sms = 1.0f / (1.0f + __expf(-e[1]));
        st.oma = 1.0f - st.lsms;
        st.oms = 1.0f - st.seas_sms;
        float is[PERIOD];
#pragma unroll
        for (int j = 0; j < PERIOD; ++j) is[j] = __expf(e[2 + j]);
        st.lev = Yb[0] / is[0];

        float* seab = seasonal + (size_t)b * SEAS_LEN;
#pragma unroll
        for (int j = 0; j < PERIOD; ++j) seab[j] = is[j];
        ts[0][l][0] = is[0];           // seasonal col 7 (= "ns_{-1}") for chunk 0
#pragma unroll
        for (int j = 0; j < PERIOD; ++j) st.sbuf[j] = is[(j + 1) % PERIOD];
#pragma unroll
        for (int j = 0; j < PERIOD; ++j)
            st.rbuf[j] = st.lsms * __builtin_amdgcn_rcpf(st.sbuf[j]);
        st.yp = 0.0f; st.sp = 1.0f; st.rnlp = 1.0f; st.rnsp = 1.0f;

        float ya[64], yb2[64];
#pragma unroll
        for (int k = 0; k < 64; k += 4)
            *(float4*)&ya[k] = *(const float4*)(Yb + k);

        // pair 0: chunks 0,1
        scan_chunk<true,  false, true>(0,  l, Yb, ya,  yb2, tl[0], ts[0], st);
        scan_chunk<false, false, true>(64, l, Yb, yb2, ya,  tl[1], ts[1], st);
        asm volatile("s_waitcnt lgkmcnt(0)" ::: "memory");
        __builtin_amdgcn_s_barrier();
        // pairs 1..14: chunks 2..29 (chunk c: cur = (c&1)?yb2:ya)
#pragma unroll 1
        for (int p = 1; p < 15; ++p) {
            const int c0 = 2 * p;
            float (*t0l)[65] = tl[c0 & 3],      (*t0s)[65] = ts[c0 & 3];
            float (*t1l)[65] = tl[(c0 + 1) & 3], (*t1s)[65] = ts[(c0 + 1) & 3];
            scan_chunk<false, false, true>(c0 * 64,      l, Yb, ya,  yb2, t0l, t0s, st);
            scan_chunk<false, false, true>(c0 * 64 + 64, l, Yb, yb2, ya,  t1l, t1s, st);
            asm volatile("s_waitcnt lgkmcnt(0)" ::: "memory");
            __builtin_amdgcn_s_barrier();
        }
        // pair 15: chunks 30 (prefetches 31's y), 31 (LAST)
        scan_chunk<false, false, true >(1920, l, Yb, ya,  yb2, tl[2], ts[2], st);
        scan_chunk<false, true,  false>(1984, l, Yb, yb2, ya,  tl[3], ts[3], st);
        asm volatile("s_waitcnt lgkmcnt(0)" ::: "memory");
        __builtin_amdgcn_s_barrier();
    } else {
        // ------- consumer wave: transpose + coalesced stores, per PAIR -------
        const int jr = l >> 4;
        const int km = (l & 15) * 4;
#pragma unroll 1
        for (int p = 0; p < 16; ++p) {
            __builtin_amdgcn_s_barrier();      // producer finished pair p
            asm volatile("" ::: "memory");
            const int c0 = 2 * p;
            drain_chunk(c0 * 64,      jr, km, r0, tl[c0 & 3],       ts[c0 & 3],       levels, seasonal);
            drain_chunk(c0 * 64 + 64, jr, km, r0, tl[(c0 + 1) & 3], ts[(c0 + 1) & 3], levels, seasonal);
            // LDS reads must retire before producer may overwrite (pair p+2,
            // which it reaches only after the NEXT barrier we join)
            asm volatile("s_waitcnt lgkmcnt(0)" ::: "memory");
        }
    }
}

// ---------------------------------------------------------------------------
// Phase 2: y_in columns only (j < 28; needs levels/seasonal). ~104 MB HBM
// (66 w + ~38 RMW fetch) at ~6.3 TB/s -> already near its BW floor.
// ---------------------------------------------------------------------------
__global__ __launch_bounds__(256) void es_windows_yin(
    const float* __restrict__ Y, const float* __restrict__ levels,
    const float* __restrict__ seasonal, float* __restrict__ out0)
{
    unsigned gid = blockIdx.x * 256 + threadIdx.x;
    unsigned wb = gid / 28u;
    int j  = (int)(gid - wb * 28u);
    int w  = (int)(wb >> 11);
    int b  = (int)(wb & (BATCH - 1));
    int t0 = w * 7;
    float y  = Y[b * N_TIME + t0 + j];
    float lv = levels[b * N_TIME + t0 + INPUT_SIZE - 1];
    float sv = seasonal[b * SEAS_LEN + t0 + j];
    out0[(size_t)wb * 67u + (unsigned)j] =
        __logf(y * __builtin_amdgcn_rcpf(lv * sv));
}

extern "C" void kernel_launch(void* const* d_in, const int* in_sizes, int n_in,
                              void* d_out, int out_size, void* d_ws, size_t ws_size,
                              hipStream_t stream) {
    const float* S    = (const float*)d_in[0];
    const float* Y    = (const float*)d_in[1];
    const float* X    = (const float*)d_in[2];
    const int*   idxs = (const int*)d_in[3];
    const float* emb  = (const float*)d_in[4];

    float* out      = (float*)d_out;
    float* out_ins  = out;                                    // (W,B,67)
    float* out_outs = out + OUT0_SIZE;                        // (W,B,7)
    float* levels   = out + OUT0_SIZE + OUT1_SIZE;            // (B,2048)
    float* seasonal = out + OUT0_SIZE + OUT1_SIZE + LEV_SIZE; // (B,2055)

    es_scan_plus<<<GRID1, 128, 0, stream>>>(
        Y, idxs, emb, X, S, levels, seasonal, out_ins, out_outs);

    es_windows_yin<<<N_YIN / 256, 256, 0, stream>>>(
        Y, levels, seasonal, out_ins);
}

// Round 9
// 354.869 us; speedup vs baseline: 1.1257x; 1.1257x over previous
//
#include <hip/hip_runtime.h>
#include <math.h>

#define BATCH 2048
#define N_TIME 2048
#define INPUT_SIZE 28
#define OUTPUT_SIZE 7
#define N_S 4
#define PERIOD 7
#define EMBED 9
#define SEAS_LEN (N_TIME + PERIOD)       // 2055
#define W_COUNT 288                      // len(range(0, 2014, 7))
#define WB_COUNT (W_COUNT * BATCH)       // 589824
#define INS_COLS 67                      // 28 + 35 + 4
#define OUT0_SIZE (WB_COUNT * INS_COLS)  // 39,518,208
#define OUT1_SIZE (WB_COUNT * OUTPUT_SIZE) // 4,128,768
#define LEV_SIZE (BATCH * N_TIME)
#define SEAS_SIZE (BATCH * SEAS_LEN)

// Work split (PROVEN r4/r6 two-kernel shape):
//   kernel1 scan blocks (0..31): producer-consumer ES recurrence.
//   kernel1 copy blocks (32..511): out0 cols [28,67) (X,S) + out1.
//   kernel2: out0 cols [0,28) (y_in; needs levels/seasonal).
// HARD LESSONS:
//   r3/r5/r7: flags/steal-loops/ABI calls in this kernel collapse regalloc.
//   r8: 133KB LDS -> 1 block/CU throttles the COPY blocks too. Keep 66.5KB.
//   r8 counters: the merged kernel is capped at 132 VGPR no matter what;
//     the old 2x64-float y buffer spilled (16.4MB scratch stores visible in
//     WRITE_SIZE every round since r3). ROUND-9: 2x32-float rolling window,
//     refilled at k==0 / k==31 with compile-time indices -> fits under 132.
#define M0_COPY (WB_COUNT * 39)              // 23,003,136 (X+S cols)
#define M_COPY  (M0_COPY + OUT1_SIZE)        // 27,131,904
#define COPY_BLOCKS 480
#define GRID1 (32 + COPY_BLOCKS)
#define N_YIN (WB_COUNT * INPUT_SIZE)        // 16,515,072 = 64512*256
#define CUNROLL 16

// ---------------------------------------------------------------------------
// Scan core: producer = software-pipelined recurrence, modular-slot sbuf/rbuf
// (s_k = ns_{k-7} known 7 steps early -> level update is ONE carried fma);
// consumer = tile transpose + coalesced stores.
// y window invariant at chunk entry (base=64c): W0 = y[base, base+32),
// W1 loaded in-chunk at k==0 <- y[base+32, base+64).
//   k in [0,31):  y = W0[k+1]
//   k in [31,63): y = W1[k-31]
//   k == 63:      y = W0[0]   (W0 refilled at k==31 <- y[base+64, base+96))
// Issue->use slack: W1 31 steps, W0 32 steps -> covers load latency.
// ---------------------------------------------------------------------------
struct ScanState {
    float lev, lsms, seas_sms, oma, oms;
    float sbuf[PERIOD];   // slot j%7 holds s_{t0+j}
    float rbuf[PERIOD];   // slot j%7 holds lsms * rcp(s_{t0+j})
    float yp, sp, rnlp, rnsp;
};

template<bool FIRST, bool LAST>
__device__ __forceinline__ void scan_chunk(
    int base, int l,
    const float* __restrict__ Yb,
    float (&W0)[32], float (&W1)[32],
    float (*__restrict__ tl)[65], float (*__restrict__ ts)[65],
    ScanState& st)
{
    tl[l][0] = st.lev;                 // carry-in: levels col `base`
#pragma unroll
    for (int k = 0; k < 64; ++k) {
        if (k == 0) {                  // W1 <- y[base+32, base+64): use @k=31
#pragma unroll
            for (int m = 0; m < 32; m += 4)
                *(float4*)&W1[m] = *(const float4*)(Yb + base + 32 + m);
        }
        if (!LAST && k == 31) {        // W0 <- y[base+64, base+96): use @k=63
#pragma unroll
            for (int m = 0; m < 32; m += 4)
                *(float4*)&W0[m] = *(const float4*)(Yb + base + 64 + m);
        }
        if (!LAST || k < 63) {         // last chunk has 63 steps
            float y  = (k < 31) ? W0[k + 1] : ((k < 63) ? W1[k - 31] : W0[0]);
            float s0 = st.sbuf[k % 7];
            float nl = fmaf(st.oma, st.lev, y * st.rbuf[k % 7]);
            st.lev = nl;
            tl[l][k + 1] = nl;         // levels col base+k+1
            if (!FIRST || k > 0) {     // finish PREVIOUS step's seasonal
                float u  = st.yp * st.rnlp;
                float ns = fmaf(st.oms, st.sp, st.seas_sms * u);
                ts[l][k] = ns;                 // seasonal col base+7+k
                st.sbuf[(k + 6) % 7] = ns;     // consumed at k+6
                if (!FIRST || k > 1)
                    st.rbuf[(k + 5) % 7] = st.lsms * st.rnsp; // for k+5
                st.rnsp = __builtin_amdgcn_rcpf(ns);
            }
            float rnl = __builtin_amdgcn_rcpf(nl);   // consumed next step
            st.yp = y; st.sp = s0; st.rnlp = rnl;
        }
    }
    if (LAST) {                        // drain pipeline: ns_{2046}
        float u  = st.yp * st.rnlp;
        float ns = fmaf(st.oms, st.sp, st.seas_sms * u);
        ts[l][63] = ns;                // seasonal col 2054
    } else {
        // slot-base drift: next chunk's t0 advances by 64 (== 1 mod 7)
        float t0s = st.sbuf[0], t0r = st.rbuf[0];
#pragma unroll
        for (int q = 0; q < PERIOD - 1; ++q) {
            st.sbuf[q] = st.sbuf[q + 1];
            st.rbuf[q] = st.rbuf[q + 1];
        }
        st.sbuf[PERIOD - 1] = t0s;
        st.rbuf[PERIOD - 1] = t0r;
    }
    asm volatile("s_waitcnt lgkmcnt(0)" ::: "memory");
    __builtin_amdgcn_s_barrier();
}

__device__ __forceinline__ void drain_chunk(
    int base, int jr, int km, int r0,
    const float (*__restrict__ tl)[65], const float (*__restrict__ ts)[65],
    float* __restrict__ levels, float* __restrict__ seasonal)
{
    __builtin_amdgcn_s_barrier();      // wait for producer to finish this tile
    asm volatile("" ::: "memory");
#pragma unroll
    for (int j0 = 0; j0 < 64; j0 += 4) {
        int j = j0 + jr;               // tile row = local batch row
        float vl[4], vs[4];
#pragma unroll
        for (int i = 0; i < 4; ++i) { vl[i] = tl[j][km + i]; vs[i] = ts[j][km + i]; }
        float4 v4; v4.x = vl[0]; v4.y = vl[1]; v4.z = vl[2]; v4.w = vl[3];
        *(float4*)(levels + (size_t)(r0 + j) * N_TIME + base + km) = v4;
        float* srow = seasonal + (size_t)(r0 + j) * SEAS_LEN + base + 7 + km;
#pragma unroll
        for (int i = 0; i < 4; ++i) srow[i] = vs[i];
    }
    // LDS reads retire before joining the next barrier (buffer reuse)
    asm volatile("s_waitcnt lgkmcnt(0)" ::: "memory");
}

__device__ __forceinline__ void copy_addr(
    unsigned g,
    const float* __restrict__ Y, const float* __restrict__ X,
    const float* __restrict__ S,
    float* __restrict__ out0, float* __restrict__ out1,
    const float*& src, float*& dst)
{
    if (g < M0_COPY) {                 // out0 cols 28..66 (X then S)
        unsigned wb = g / 39u;
        int jj = (int)(g - wb * 39u);
        int w  = (int)(wb >> 11);
        int b  = (int)(wb & (BATCH - 1));
        src = (jj < 35) ? &X[b * N_TIME + w * 7 + jj]
                        : &S[b * N_S + (jj - 35)];
        dst = &out0[(size_t)wb * 67u + 28u + (unsigned)jj];
    } else {                           // out1
        unsigned e  = g - M0_COPY;
        unsigned wb = e / 7u;
        int m  = (int)(e - wb * 7u);
        int w  = (int)(wb >> 11);
        int b  = (int)(wb & (BATCH - 1));
        src = &Y[b * N_TIME + w * 7 + INPUT_SIZE + m];
        dst = &out1[e];
    }
}

__global__ __launch_bounds__(128, 1) void es_scan_plus(
    const float* __restrict__ Y, const int* __restrict__ idxs,
    const float* __restrict__ emb, const float* __restrict__ X,
    const float* __restrict__ S,
    float* __restrict__ levels, float* __restrict__ seasonal,
    float* __restrict__ out0, float* __restrict__ out1)
{
    __shared__ float tl[2][64][65];    // 66,560 B total -> 2 blocks/CU
    __shared__ float ts[2][64][65];
    const int tid = threadIdx.x;
    const int l   = tid & 63;

    if (blockIdx.x >= 32) {
        // ------- copy blocks: 16-deep gather/scatter (64 B in flight/thread) ---
        const unsigned stride = COPY_BLOCKS * 128;
        unsigned g = (blockIdx.x - 32) * 128 + tid;
#pragma unroll 1
        for (; g + (CUNROLL - 1) * stride < M_COPY; g += stride * CUNROLL) {
            const float* src[CUNROLL]; float* dst[CUNROLL]; float v[CUNROLL];
#pragma unroll
            for (int u = 0; u < CUNROLL; ++u)
                copy_addr(g + (unsigned)u * stride, Y, X, S, out0, out1, src[u], dst[u]);
#pragma unroll
            for (int u = 0; u < CUNROLL; ++u) v[u] = *src[u];
#pragma unroll
            for (int u = 0; u < CUNROLL; ++u) *dst[u] = v[u];
        }
#pragma unroll 1
        for (; g < M_COPY; g += stride) {
            const float* src; float* dst;
            copy_addr(g, Y, X, S, out0, out1, src, dst);
            *dst = *src;
        }
        return;
    }

    const int r0 = blockIdx.x * 64;
    if (tid < 64) {
        // ---------------- producer wave: the recurrence ----------------
        const int b = r0 + l;
        const float* Yb = Y + (size_t)b * N_TIME;
        const float* e  = emb + (size_t)idxs[b] * EMBED;
        ScanState st;
        st.lsms     = 1.0f / (1.0f + __expf(-e[0]));
        st.seas_sms = 1.0f / (1.0f + __expf(-e[1]));
        st.oma = 1.0f - st.lsms;
        st.oms = 1.0f - st.seas_sms;
        float is[PERIOD];
#pragma unroll
        for (int j = 0; j < PERIOD; ++j) is[j] = __expf(e[2 + j]);
        st.lev = Yb[0] / is[0];

        float* seab = seasonal + (size_t)b * SEAS_LEN;
#pragma unroll
        for (int j = 0; j < PERIOD; ++j) seab[j] = is[j];
        ts[0][l][0] = is[0];           // seasonal col 7 (= "ns_{-1}") for chunk 0
#pragma unroll
        for (int j = 0; j < PERIOD; ++j) st.sbuf[j] = is[(j + 1) % PERIOD];
#pragma unroll
        for (int j = 0; j < PERIOD; ++j)
            st.rbuf[j] = st.lsms * __builtin_amdgcn_rcpf(st.sbuf[j]);
        st.yp = 0.0f; st.sp = 1.0f; st.rnlp = 1.0f; st.rnsp = 1.0f;

        float W0[32], W1[32];
#pragma unroll
        for (int m = 0; m < 32; m += 4)    // W0 invariant for chunk 0
            *(float4*)&W0[m] = *(const float4*)(Yb + m);

        scan_chunk<true, false>(0, l, Yb, W0, W1, tl[0], ts[0], st);
#pragma unroll 1
        for (int c = 1; c < 31; ++c)
            scan_chunk<false, false>(c * 64, l, Yb, W0, W1, tl[c & 1], ts[c & 1], st);
        scan_chunk<false, true>(1984, l, Yb, W0, W1, tl[1], ts[1], st);
    } else {
        // ---------------- consumer wave: transpose + coalesced stores ----------
        const int jr = l >> 4;
        const int km = (l & 15) * 4;
#pragma unroll 1
        for (int c = 0; c < 32; ++c)
            drain_chunk(c * 64, jr, km, r0, tl[c & 1], ts[c & 1], levels, seasonal);
    }
}

// ---------------------------------------------------------------------------
// Phase 2: y_in columns only (j < 28; needs levels/seasonal). ~104 MB HBM
// at ~6.3 TB/s -> near its BW floor.
// ---------------------------------------------------------------------------
__global__ __launch_bounds__(256) void es_windows_yin(
    const float* __restrict__ Y, const float* __restrict__ levels,
    const float* __restrict__ seasonal, float* __restrict__ out0)
{
    unsigned gid = blockIdx.x * 256 + threadIdx.x;
    unsigned wb = gid / 28u;
    int j  = (int)(gid - wb * 28u);
    int w  = (int)(wb >> 11);
    int b  = (int)(wb & (BATCH - 1));
    int t0 = w * 7;
    float y  = Y[b * N_TIME + t0 + j];
    float lv = levels[b * N_TIME + t0 + INPUT_SIZE - 1];
    float sv = seasonal[b * SEAS_LEN + t0 + j];
    out0[(size_t)wb * 67u + (unsigned)j] =
        __logf(y * __builtin_amdgcn_rcpf(lv * sv));
}

extern "C" void kernel_launch(void* const* d_in, const int* in_sizes, int n_in,
                              void* d_out, int out_size, void* d_ws, size_t ws_size,
                              hipStream_t stream) {
    const float* S    = (const float*)d_in[0];
    const float* Y    = (const float*)d_in[1];
    const float* X    = (const float*)d_in[2];
    const int*   idxs = (const int*)d_in[3];
    const float* emb  = (const float*)d_in[4];

    float* out      = (float*)d_out;
    float* out_ins  = out;                                    // (W,B,67)
    float* out_outs = out + OUT0_SIZE;                        // (W,B,7)
    float* levels   = out + OUT0_SIZE + OUT1_SIZE;            // (B,2048)
    float* seasonal = out + OUT0_SIZE + OUT1_SIZE + LEV_SIZE; // (B,2055)

    es_scan_plus<<<GRID1, 128, 0, stream>>>(
        Y, idxs, emb, X, S, levels, seasonal, out_ins, out_outs);

    es_windows_yin<<<N_YIN / 256, 256, 0, stream>>>(
        Y, levels, seasonal, out_ins);
}